// Round 1
// baseline (1382.425 us; speedup 1.0000x reference)
//
#include <hip/hip_runtime.h>
#include <hip/hip_bf16.h>
#include <stdint.h>

// Problem constants
#define B_   4
#define C_   256
#define H_   200
#define W_   336
#define OC_  512
#define HP_  202           // H + 2 (pad)
#define WP_  338           // W + 2 (pad)
#define M_   (B_*H_*W_)    // 268800 pixels = 2100 * 128 exactly
#define MTILES (M_/128)    // 2100
#define OUT0_ (M_*18)      // 4,838,400 cls elements
#define OUT_TOTAL_ (M_*54) // 14,515,200

// Workspace layout (bytes)
#define XP_ELEMS  ((size_t)B_*HP_*WP_*C_)   // 69,914,624
#define XP_BYTES  (XP_ELEMS*2)              // ~139.8 MB
#define W1T_ELEMS ((size_t)9*OC_*C_)        // 1,179,648
#define W1T_OFF   XP_BYTES
#define WHB_OFF   (W1T_OFF + W1T_ELEMS*2)
// total ws need ~142.3 MB

typedef unsigned short ushortT;
typedef __attribute__((ext_vector_type(8))) short bf16x8;   // 8 bf16 = 4 VGPR
typedef __attribute__((ext_vector_type(4))) float f32x4;

static __device__ __forceinline__ ushortT f2bf(float x) {
    union { float f; uint32_t u; } v; v.f = x;
    uint32_t r = v.u + 0x7fff + ((v.u >> 16) & 1);   // RNE
    return (ushortT)(r >> 16);
}

// ---------------------------------------------------------------------------
// Pre-pass 1: NCHW fp32 -> padded NHWC bf16 via LDS tile transpose.
// Block = (b, h, wchunk of 64); loops 4 c-chunks of 64.
__global__ __launch_bounds__(256) void pad_transpose(const float* __restrict__ X,
                                                     ushortT* __restrict__ Xp) {
    int bid = blockIdx.x;
    int wc = bid % 6; int bh = bid / 6;
    int h = bh % H_;  int b = bh / H_;
    int w0 = wc * 64;
    int t = threadIdx.x;
    __shared__ ushortT tile[64 * 65];   // [c][w], stride 65 breaks bank conflicts

    for (int c0 = 0; c0 < C_; c0 += 64) {
        if (c0) __syncthreads();
        int col  = t & 63;     // w within chunk
        int rowb = t >> 6;     // wave id -> row group
        #pragma unroll
        for (int rr = 0; rr < 16; ++rr) {
            int row = rowb * 16 + rr;      // c within chunk
            int w = w0 + col;
            float val = 0.f;
            if (w < W_)
                val = X[(((size_t)(b*C_ + c0 + row))*H_ + h)*W_ + w];
            tile[row*65 + col] = f2bf(val);
        }
        __syncthreads();
        // write: 4 threads per pixel, each 16 c (32B)
        int pixel = t >> 2;
        int csub  = (t & 3) * 16;
        int w = w0 + pixel;
        if (w < W_) {
            union { ushortT u[16]; uint4 q[2]; } vals;
            #pragma unroll
            for (int j = 0; j < 16; ++j)
                vals.u[j] = tile[(csub + j)*65 + pixel];
            size_t dst = (((size_t)b*HP_ + (h+1))*WP_ + (w+1))*C_ + c0 + csub;
            *(uint4*)(Xp + dst)     = vals.q[0];
            *(uint4*)(Xp + dst + 8) = vals.q[1];
        }
    }
}

// Pre-pass 2: W1 [oc][c][3][3] fp32 -> W1t [rs][oc][c] bf16
__global__ __launch_bounds__(256) void prep_w1(const float* __restrict__ W1,
                                               ushortT* __restrict__ W1t) {
    int t = blockIdx.x * 256 + threadIdx.x;   // over 512*256
    if (t >= OC_*C_) return;
    const float* src = W1 + (size_t)t * 9;
    #pragma unroll
    for (int rs = 0; rs < 9; ++rs)
        W1t[(size_t)rs*OC_*C_ + t] = f2bf(src[rs]);
}

// Pre-pass 3: Wc[18][512], Wb[36][512] fp32 -> Whb[64][512] bf16 (rows 54..63 zero)
__global__ __launch_bounds__(256) void prep_whb(const float* __restrict__ Wc,
                                                const float* __restrict__ Wb,
                                                ushortT* __restrict__ Whb) {
    int t = blockIdx.x * 256 + threadIdx.x;   // 64*512 = 32768
    if (t >= 64*512) return;
    int o = t >> 9, oc = t & 511;
    float v = 0.f;
    if (o < 18) v = Wc[o*512 + oc];
    else if (o < 54) v = Wb[(o-18)*512 + oc];
    Whb[t] = f2bf(v);
}

// Pre-pass 4: init output with head biases (atomic partials accumulate on top)
__global__ __launch_bounds__(256) void init_out(const float* __restrict__ bc,
                                                const float* __restrict__ bb,
                                                float* __restrict__ out) {
    int i = blockIdx.x * 256 + threadIdx.x;
    if (i < OUT0_) out[i] = bc[i % 18];
    else if (i < OUT_TOTAL_) out[i] = bb[(i - OUT0_) % 36];
}

// ---------------------------------------------------------------------------
// Main fused kernel: implicit-GEMM conv3x3 (M=268800, N=512/4 blocks, K=2304)
// + bias + ReLU + 1x1 head GEMM (54 outputs) with atomic partial accumulation.
#define FP_ 136   // Fsm row stride (padded; 136*2=272B is 16B-aligned per row)

__global__ __launch_bounds__(256, 2) void conv_rpn(
    const ushortT* __restrict__ Xp, const ushortT* __restrict__ W1t,
    const float* __restrict__ b1,  const ushortT* __restrict__ Whb,
    float* __restrict__ out)
{
    __shared__ ushortT Asm[128*32];     // [m][k] 8KB
    __shared__ ushortT Bsm[128*32];     // [n][k] 8KB
    __shared__ ushortT Fsm[128*FP_];    // feat tile [m][oc] ~34KB

    const int tid  = threadIdx.x;
    const int wave = tid >> 6;
    const int lane = tid & 63;
    const int col  = lane & 15;
    const int quad = lane >> 4;

    const int mtile = blockIdx.x >> 2;
    const int nblk  = blockIdx.x & 3;
    const int oc0   = nblk << 7;

    // Staging: wave covers rows [wave*32, wave*32+32) in two chunks of 16.
    const int arow0 = wave*32 + (lane >> 2);
    const int csub  = (lane & 3) * 8;

    size_t pixbase[2];
    #pragma unroll
    for (int i = 0; i < 2; ++i) {
        int m = mtile*128 + arow0 + i*16;
        int b = m / (H_*W_);
        int rem = m % (H_*W_);
        int h = rem / W_;
        int w = rem % W_;
        pixbase[i] = (((size_t)b*HP_ + h)*WP_ + w)*C_ + csub;
    }
    const size_t bbase = ((size_t)(oc0 + arow0))*C_ + csub;

    f32x4 acc[4][4] = {};
    const int wm = (wave & 1) * 64;
    const int wn = (wave >> 1) * 64;

    for (int rs = 0; rs < 9; ++rs) {
        const int roff = ((rs/3)*WP_ + (rs%3)) * C_;
        const size_t wsrc = (size_t)rs*OC_*C_;
        for (int cs = 0; cs < C_; cs += 32) {
            __syncthreads();
            #pragma unroll
            for (int i = 0; i < 2; ++i) {
                const ushortT* g = Xp + pixbase[i] + roff + cs;
                ushortT* l = Asm + (wave*32 + i*16)*32;
                __builtin_amdgcn_global_load_lds(
                    (const __attribute__((address_space(1))) uint32_t*)g,
                    (__attribute__((address_space(3))) uint32_t*)l, 16, 0, 0);
            }
            #pragma unroll
            for (int i = 0; i < 2; ++i) {
                const ushortT* g = W1t + wsrc + bbase + (size_t)i*16*C_ + cs;
                ushortT* l = Bsm + (wave*32 + i*16)*32;
                __builtin_amdgcn_global_load_lds(
                    (const __attribute__((address_space(1))) uint32_t*)g,
                    (__attribute__((address_space(3))) uint32_t*)l, 16, 0, 0);
            }
            __syncthreads();

            bf16x8 af[4], bfr[4];
            #pragma unroll
            for (int mt = 0; mt < 4; ++mt)
                af[mt] = *(const bf16x8*)&Asm[(wm + mt*16 + col)*32 + quad*8];
            #pragma unroll
            for (int nt = 0; nt < 4; ++nt)
                bfr[nt] = *(const bf16x8*)&Bsm[(wn + nt*16 + col)*32 + quad*8];
            #pragma unroll
            for (int mt = 0; mt < 4; ++mt)
                #pragma unroll
                for (int nt = 0; nt < 4; ++nt)
                    acc[mt][nt] = __builtin_amdgcn_mfma_f32_16x16x32_bf16(
                        af[mt], bfr[nt], acc[mt][nt], 0, 0, 0);
        }
    }

    // Epilogue: +b1, ReLU, feat tile -> LDS (bf16)
    __syncthreads();
    float b1v[4];
    #pragma unroll
    for (int nt = 0; nt < 4; ++nt) b1v[nt] = b1[oc0 + wn + nt*16 + col];
    #pragma unroll
    for (int mt = 0; mt < 4; ++mt)
        #pragma unroll
        for (int nt = 0; nt < 4; ++nt)
            #pragma unroll
            for (int rg = 0; rg < 4; ++rg) {
                float v = acc[mt][nt][rg] + b1v[nt];
                v = fmaxf(v, 0.f);
                Fsm[(wm + mt*16 + quad*4 + rg)*FP_ + wn + nt*16 + col] = f2bf(v);
            }
    __syncthreads();

    // Head GEMM: M=128 (pixels), N=64 (54 used), K=128 (this block's oc slice).
    // Each wave: 32 m-rows x 64 n.
    f32x4 hacc[2][4] = {};
    #pragma unroll
    for (int ks = 0; ks < 4; ++ks) {
        bf16x8 ah[2];
        #pragma unroll
        for (int mt = 0; mt < 2; ++mt)
            ah[mt] = *(const bf16x8*)&Fsm[(wave*32 + mt*16 + col)*FP_ + ks*32 + quad*8];
        #pragma unroll
        for (int nt = 0; nt < 4; ++nt) {
            bf16x8 bh = *(const bf16x8*)&Whb[(nt*16 + col)*512 + oc0 + ks*32 + quad*8];
            #pragma unroll
            for (int mt = 0; mt < 2; ++mt)
                hacc[mt][nt] = __builtin_amdgcn_mfma_f32_16x16x32_bf16(
                    ah[mt], bh, hacc[mt][nt], 0, 0, 0);
        }
    }

    // Atomic partial accumulation into interleaved outputs.
    #pragma unroll
    for (int mt = 0; mt < 2; ++mt) {
        int mbase = mtile*128 + wave*32 + mt*16 + quad*4;
        #pragma unroll
        for (int nt = 0; nt < 4; ++nt) {
            int o = nt*16 + col;
            #pragma unroll
            for (int rg = 0; rg < 4; ++rg) {
                float v = hacc[mt][nt][rg];
                size_t p = (size_t)(mbase + rg);
                if (o < 18)      atomicAdd(out + p*18 + o, v);
                else if (o < 54) atomicAdd(out + OUT0_ + p*36 + (o - 18), v);
            }
        }
    }
}

// ---------------------------------------------------------------------------
extern "C" void kernel_launch(void* const* d_in, const int* in_sizes, int n_in,
                              void* d_out, int out_size, void* d_ws, size_t ws_size,
                              hipStream_t stream) {
    const float* X  = (const float*)d_in[0];
    const float* W1 = (const float*)d_in[1];
    const float* b1 = (const float*)d_in[2];
    const float* Wc = (const float*)d_in[3];
    const float* bc = (const float*)d_in[4];
    const float* Wb = (const float*)d_in[5];
    const float* bb = (const float*)d_in[6];
    float* out = (float*)d_out;

    ushortT* Xp  = (ushortT*)d_ws;
    ushortT* W1t = (ushortT*)((char*)d_ws + W1T_OFF);
    ushortT* Whb = (ushortT*)((char*)d_ws + WHB_OFF);

    // zero the padded input buffer (borders must be 0; ws is poisoned each call)
    hipMemsetAsync(d_ws, 0, XP_BYTES, stream);
    pad_transpose<<<B_*H_*6, 256, 0, stream>>>(X, Xp);
    prep_w1<<<(OC_*C_ + 255)/256, 256, 0, stream>>>(W1, W1t);
    prep_whb<<<(64*512 + 255)/256, 256, 0, stream>>>(Wc, Wb, Whb);
    init_out<<<(OUT_TOTAL_ + 255)/256, 256, 0, stream>>>(bc, bb, out);
    conv_rpn<<<MTILES*4, 256, 0, stream>>>(Xp, W1t, b1, Whb, out);
}

// Round 2
// 1207.730 us; speedup vs baseline: 1.1446x; 1.1446x over previous
//
#include <hip/hip_runtime.h>
#include <hip/hip_bf16.h>
#include <stdint.h>

// Problem constants
#define B_   4
#define C_   256
#define H_   200
#define W_   336
#define OC_  512
#define HP_  202           // H + 2 (pad)
#define WP_  338           // W + 2 (pad)
#define M_   (B_*H_*W_)    // 268800 pixels = 2100 * 128 exactly
#define MTILES (M_/128)    // 2100
#define OUT0_ (M_*18)      // 4,838,400 cls elements
#define OUT_TOTAL_ (M_*54) // 14,515,200

// Workspace layout (bytes)
#define XP_ELEMS  ((size_t)B_*HP_*WP_*C_)   // 69,914,624
#define XP_BYTES  (XP_ELEMS*2)              // ~139.8 MB
#define W1T_ELEMS ((size_t)9*OC_*C_)        // 1,179,648
#define W1T_OFF   XP_BYTES
#define WHB_OFF   (W1T_OFF + W1T_ELEMS*2)

typedef unsigned short ushortT;
typedef __attribute__((ext_vector_type(8))) short bf16x8;   // 8 bf16 = 4 VGPR
typedef __attribute__((ext_vector_type(4))) float f32x4;

static __device__ __forceinline__ ushortT f2bf(float x) {
    union { float f; uint32_t u; } v; v.f = x;
    uint32_t r = v.u + 0x7fff + ((v.u >> 16) & 1);   // RNE
    return (ushortT)(r >> 16);
}

// ---------------------------------------------------------------------------
// Pre-pass 0: zero only the halo of the padded buffer (ws is re-poisoned to
// 0xAA before every call; interior is fully overwritten by pad_transpose).
// Halo pixels per batch: h=0 row (338), h=201 row (338), w={0,337} for
// h=1..200 (400) => 1076 pixels * 4 batches; each pixel = 256ch = 32 uint4.
__global__ __launch_bounds__(256) void zero_halo(ushortT* __restrict__ Xp) {
    int i = blockIdx.x * 256 + threadIdx.x;
    if (i >= 4 * 1076 * 32) return;
    int pix = i >> 5, ch = (i & 31) * 8;
    int b = pix / 1076, r = pix % 1076;
    int h, w;
    if (r < 338)      { h = 0;   w = r; }
    else if (r < 676) { h = 201; w = r - 338; }
    else { r -= 676; h = 1 + (r >> 1); w = (r & 1) ? 337 : 0; }
    size_t dst = (((size_t)b*HP_ + h)*WP_ + w)*C_ + ch;
    *(uint4*)(Xp + dst) = make_uint4(0, 0, 0, 0);
}

// Pre-pass 1: NCHW fp32 -> padded NHWC bf16 via LDS tile transpose.
__global__ __launch_bounds__(256) void pad_transpose(const float* __restrict__ X,
                                                     ushortT* __restrict__ Xp) {
    int bid = blockIdx.x;
    int wc = bid % 6; int bh = bid / 6;
    int h = bh % H_;  int b = bh / H_;
    int w0 = wc * 64;
    int t = threadIdx.x;
    __shared__ ushortT tile[64 * 65];

    for (int c0 = 0; c0 < C_; c0 += 64) {
        if (c0) __syncthreads();
        int col  = t & 63;
        int rowb = t >> 6;
        #pragma unroll
        for (int rr = 0; rr < 16; ++rr) {
            int row = rowb * 16 + rr;
            int w = w0 + col;
            float val = 0.f;
            if (w < W_)
                val = X[(((size_t)(b*C_ + c0 + row))*H_ + h)*W_ + w];
            tile[row*65 + col] = f2bf(val);
        }
        __syncthreads();
        int pixel = t >> 2;
        int csub  = (t & 3) * 16;
        int w = w0 + pixel;
        if (w < W_) {
            union { ushortT u[16]; uint4 q[2]; } vals;
            #pragma unroll
            for (int j = 0; j < 16; ++j)
                vals.u[j] = tile[(csub + j)*65 + pixel];
            size_t dst = (((size_t)b*HP_ + (h+1))*WP_ + (w+1))*C_ + c0 + csub;
            *(uint4*)(Xp + dst)     = vals.q[0];
            *(uint4*)(Xp + dst + 8) = vals.q[1];
        }
    }
}

// Pre-pass 2: W1 [oc][c][3][3] fp32 -> W1t [rs][oc][c] bf16
__global__ __launch_bounds__(256) void prep_w1(const float* __restrict__ W1,
                                               ushortT* __restrict__ W1t) {
    int t = blockIdx.x * 256 + threadIdx.x;
    if (t >= OC_*C_) return;
    const float* src = W1 + (size_t)t * 9;
    #pragma unroll
    for (int rs = 0; rs < 9; ++rs)
        W1t[(size_t)rs*OC_*C_ + t] = f2bf(src[rs]);
}

// Pre-pass 3: Wc[18][512], Wb[36][512] -> Whb[64][512] bf16 (rows 54..63 zero)
__global__ __launch_bounds__(256) void prep_whb(const float* __restrict__ Wc,
                                                const float* __restrict__ Wb,
                                                ushortT* __restrict__ Whb) {
    int t = blockIdx.x * 256 + threadIdx.x;
    if (t >= 64*512) return;
    int o = t >> 9, oc = t & 511;
    float v = 0.f;
    if (o < 18) v = Wc[o*512 + oc];
    else if (o < 54) v = Wb[(o-18)*512 + oc];
    Whb[t] = f2bf(v);
}

// Pre-pass 4: init output with head biases (atomic partials accumulate on top)
__global__ __launch_bounds__(256) void init_out(const float* __restrict__ bc,
                                                const float* __restrict__ bb,
                                                float* __restrict__ out) {
    int i = blockIdx.x * 256 + threadIdx.x;
    if (i < OUT0_) out[i] = bc[i % 18];
    else if (i < OUT_TOTAL_) out[i] = bb[(i - OUT0_) % 36];
}

// ---------------------------------------------------------------------------
// Main fused kernel: implicit-GEMM conv3x3 (M=268800, N=512 in 4 blocks of
// 128, K=2304) + bias + ReLU + 1x1 head GEMM (54 outputs), atomic partials.
//
// LDS: Asm/Bsm (16KB, K-loop) UNIONed with Fsm (34KB, epilogue) -> 34.8KB
// dynamic -> 4 blocks/CU.
// Bank conflicts: XOR-swizzled staging (lane's global chunk choice) so the
// fragment ds_read_b128s are 2-way (free) instead of 8-way.
// XCD locality: 4 nblk of one mtile share blockIdx%8 within a 32-block
// window -> same XCD L2 (round-robin dispatch) -> A-tile reuse + local
// atomic RMW.
#define FP_ 136   // Fsm row stride (elements); 272B rows, 16B-aligned

#define GRID_GROUPS ((MTILES + 7) / 8)            // 263
#define CONV_GRID   (GRID_GROUPS * 32)            // 8416 (16 idle blocks)

__global__ __launch_bounds__(256, 4) void conv_rpn(
    const ushortT* __restrict__ Xp, const ushortT* __restrict__ W1t,
    const float* __restrict__ b1,  const ushortT* __restrict__ Whb,
    float* __restrict__ out)
{
    extern __shared__ ushortT smem[];
    ushortT* Asm = smem;              // [128][32]  8KB  (K-loop)
    ushortT* Bsm = smem + 128*32;     // [128][32]  8KB  (K-loop)
    ushortT* Fsm = smem;              // [128][FP_] 34KB (epilogue, overlaps)

    const int tid  = threadIdx.x;
    const int wave = tid >> 6;
    const int lane = tid & 63;
    const int col  = lane & 15;
    const int quad = lane >> 4;

    // XCD-aware decode: blocks {g*32 + x, +8, +16, +24} (same XCD x under
    // round-robin) are the 4 nblks of mtile g*8+x.
    const int bidx   = blockIdx.x;
    const int grp    = bidx >> 5;
    const int within = bidx & 31;
    const int mtile  = grp * 8 + (within & 7);
    const int nblk   = within >> 3;
    if (mtile >= MTILES) return;
    const int oc0 = nblk << 7;

    // Staging: wave covers rows [wave*32, wave*32+32) in two chunks of 16.
    // XOR swizzle: lane (row=lane>>2) fetches logical k-chunk
    // (lane&3)^((lane>>3)&3) so physical LDS layout is swizzled.
    const int arow0 = wave*32 + (lane >> 2);
    const int csub  = (((lane & 3) ^ ((lane >> 3) & 3)) * 8);

    size_t pixbase[2];
    #pragma unroll
    for (int i = 0; i < 2; ++i) {
        int m = mtile*128 + arow0 + i*16;
        int b = m / (H_*W_);
        int rem = m % (H_*W_);
        int h = rem / W_;
        int w = rem % W_;
        pixbase[i] = (((size_t)b*HP_ + h)*WP_ + w)*C_ + csub;
    }
    const size_t bbase = ((size_t)(oc0 + arow0))*C_ + csub;

    f32x4 acc[4][4] = {};
    const int wm = (wave & 1) * 64;
    const int wn = (wave >> 1) * 64;
    const int swz = (quad ^ ((col >> 1) & 3)) * 8;   // de-swizzle for reads

    for (int rs = 0; rs < 9; ++rs) {
        const int roff = ((rs/3)*WP_ + (rs%3)) * C_;
        const size_t wsrc = (size_t)rs*OC_*C_;
        for (int cs = 0; cs < C_; cs += 32) {
            __syncthreads();
            #pragma unroll
            for (int i = 0; i < 2; ++i) {
                const ushortT* g = Xp + pixbase[i] + roff + cs;
                ushortT* l = Asm + (wave*32 + i*16)*32;
                __builtin_amdgcn_global_load_lds(
                    (const __attribute__((address_space(1))) uint32_t*)g,
                    (__attribute__((address_space(3))) uint32_t*)l, 16, 0, 0);
            }
            #pragma unroll
            for (int i = 0; i < 2; ++i) {
                const ushortT* g = W1t + wsrc + bbase + (size_t)i*16*C_ + cs;
                ushortT* l = Bsm + (wave*32 + i*16)*32;
                __builtin_amdgcn_global_load_lds(
                    (const __attribute__((address_space(1))) uint32_t*)g,
                    (__attribute__((address_space(3))) uint32_t*)l, 16, 0, 0);
            }
            __syncthreads();

            bf16x8 af[4], bfr[4];
            #pragma unroll
            for (int mt = 0; mt < 4; ++mt)
                af[mt] = *(const bf16x8*)&Asm[(wm + mt*16 + col)*32 + swz];
            #pragma unroll
            for (int nt = 0; nt < 4; ++nt)
                bfr[nt] = *(const bf16x8*)&Bsm[(wn + nt*16 + col)*32 + swz];
            #pragma unroll
            for (int mt = 0; mt < 4; ++mt)
                #pragma unroll
                for (int nt = 0; nt < 4; ++nt)
                    acc[mt][nt] = __builtin_amdgcn_mfma_f32_16x16x32_bf16(
                        af[mt], bfr[nt], acc[mt][nt], 0, 0, 0);
        }
    }

    // Epilogue: +b1, ReLU, feat tile -> LDS (bf16). Fsm overlaps Asm/Bsm;
    // the barrier guarantees all waves are done reading them.
    __syncthreads();
    float b1v[4];
    #pragma unroll
    for (int nt = 0; nt < 4; ++nt) b1v[nt] = b1[oc0 + wn + nt*16 + col];
    #pragma unroll
    for (int mt = 0; mt < 4; ++mt)
        #pragma unroll
        for (int nt = 0; nt < 4; ++nt)
            #pragma unroll
            for (int rg = 0; rg < 4; ++rg) {
                float v = acc[mt][nt][rg] + b1v[nt];
                v = fmaxf(v, 0.f);
                Fsm[(wm + mt*16 + quad*4 + rg)*FP_ + wn + nt*16 + col] = f2bf(v);
            }
    __syncthreads();

    // Head GEMM: M=128 pixels, N=64 (54 used), K=128 (this block's oc slice)
    f32x4 hacc[2][4] = {};
    #pragma unroll
    for (int ks = 0; ks < 4; ++ks) {
        bf16x8 ah[2];
        #pragma unroll
        for (int mt = 0; mt < 2; ++mt)
            ah[mt] = *(const bf16x8*)&Fsm[(wave*32 + mt*16 + col)*FP_ + ks*32 + quad*8];
        #pragma unroll
        for (int nt = 0; nt < 4; ++nt) {
            bf16x8 bh = *(const bf16x8*)&Whb[(nt*16 + col)*512 + oc0 + ks*32 + quad*8];
            #pragma unroll
            for (int mt = 0; mt < 2; ++mt)
                hacc[mt][nt] = __builtin_amdgcn_mfma_f32_16x16x32_bf16(
                    ah[mt], bh, hacc[mt][nt], 0, 0, 0);
        }
    }

    // Atomic partial accumulation into interleaved outputs.
    #pragma unroll
    for (int mt = 0; mt < 2; ++mt) {
        int mbase = mtile*128 + wave*32 + mt*16 + quad*4;
        #pragma unroll
        for (int nt = 0; nt < 4; ++nt) {
            int o = nt*16 + col;
            #pragma unroll
            for (int rg = 0; rg < 4; ++rg) {
                float v = hacc[mt][nt][rg];
                size_t p = (size_t)(mbase + rg);
                if (o < 18)      atomicAdd(out + p*18 + o, v);
                else if (o < 54) atomicAdd(out + OUT0_ + p*36 + (o - 18), v);
            }
        }
    }
}

// ---------------------------------------------------------------------------
extern "C" void kernel_launch(void* const* d_in, const int* in_sizes, int n_in,
                              void* d_out, int out_size, void* d_ws, size_t ws_size,
                              hipStream_t stream) {
    const float* X  = (const float*)d_in[0];
    const float* W1 = (const float*)d_in[1];
    const float* b1 = (const float*)d_in[2];
    const float* Wc = (const float*)d_in[3];
    const float* bc = (const float*)d_in[4];
    const float* Wb = (const float*)d_in[5];
    const float* bb = (const float*)d_in[6];
    float* out = (float*)d_out;

    ushortT* Xp  = (ushortT*)d_ws;
    ushortT* W1t = (ushortT*)((char*)d_ws + W1T_OFF);
    ushortT* Whb = (ushortT*)((char*)d_ws + WHB_OFF);

    zero_halo<<<(4*1076*32 + 255)/256, 256, 0, stream>>>(Xp);
    pad_transpose<<<B_*H_*6, 256, 0, stream>>>(X, Xp);
    prep_w1<<<(OC_*C_ + 255)/256, 256, 0, stream>>>(W1, W1t);
    prep_whb<<<(64*512 + 255)/256, 256, 0, stream>>>(Wc, Wb, Whb);
    init_out<<<(OUT_TOTAL_ + 255)/256, 256, 0, stream>>>(bc, bb, out);
    conv_rpn<<<CONV_GRID, 256, 128*FP_*sizeof(ushortT), stream>>>(
        Xp, W1t, b1, Whb, out);
}

// Round 3
// 1140.391 us; speedup vs baseline: 1.2122x; 1.0590x over previous
//
#include <hip/hip_runtime.h>
#include <hip/hip_bf16.h>
#include <stdint.h>

// Problem constants
#define B_   4
#define C_   256
#define H_   200
#define W_   336
#define OC_  512
#define HP_  202           // H + 2 (pad)
#define WP_  338           // W + 2 (pad)
#define M_   (B_*H_*W_)    // 268800 pixels = 2100 * 128 exactly
#define MTILES (M_/128)    // 2100
#define OUT0_ (M_*18)      // 4,838,400 cls elements
#define OUT_TOTAL_ (M_*54) // 14,515,200

// Workspace layout (bytes)
#define XP_ELEMS  ((size_t)B_*HP_*WP_*C_)   // 69,914,624
#define XP_BYTES  (XP_ELEMS*2)              // ~139.8 MB
#define W1T_ELEMS ((size_t)9*OC_*C_)        // 1,179,648
#define W1T_OFF   XP_BYTES
#define WHB_OFF   (W1T_OFF + W1T_ELEMS*2)

typedef unsigned short ushortT;
typedef __attribute__((ext_vector_type(8))) short bf16x8;   // 8 bf16 = 4 VGPR
typedef __attribute__((ext_vector_type(4))) float f32x4;

static __device__ __forceinline__ ushortT f2bf(float x) {
    union { float f; uint32_t u; } v; v.f = x;
    uint32_t r = v.u + 0x7fff + ((v.u >> 16) & 1);   // RNE
    return (ushortT)(r >> 16);
}

// ---------------------------------------------------------------------------
// Pre-pass 0: zero only the halo of the padded buffer.
__global__ __launch_bounds__(256) void zero_halo(ushortT* __restrict__ Xp) {
    int i = blockIdx.x * 256 + threadIdx.x;
    if (i >= 4 * 1076 * 32) return;
    int pix = i >> 5, ch = (i & 31) * 8;
    int b = pix / 1076, r = pix % 1076;
    int h, w;
    if (r < 338)      { h = 0;   w = r; }
    else if (r < 676) { h = 201; w = r - 338; }
    else { r -= 676; h = 1 + (r >> 1); w = (r & 1) ? 337 : 0; }
    size_t dst = (((size_t)b*HP_ + h)*WP_ + w)*C_ + ch;
    *(uint4*)(Xp + dst) = make_uint4(0, 0, 0, 0);
}

// Pre-pass 1: NCHW fp32 -> padded NHWC bf16 via LDS tile transpose.
__global__ __launch_bounds__(256) void pad_transpose(const float* __restrict__ X,
                                                     ushortT* __restrict__ Xp) {
    int bid = blockIdx.x;
    int wc = bid % 6; int bh = bid / 6;
    int h = bh % H_;  int b = bh / H_;
    int w0 = wc * 64;
    int t = threadIdx.x;
    __shared__ ushortT tile[64 * 65];

    for (int c0 = 0; c0 < C_; c0 += 64) {
        if (c0) __syncthreads();
        int col  = t & 63;
        int rowb = t >> 6;
        #pragma unroll
        for (int rr = 0; rr < 16; ++rr) {
            int row = rowb * 16 + rr;
            int w = w0 + col;
            float val = 0.f;
            if (w < W_)
                val = X[(((size_t)(b*C_ + c0 + row))*H_ + h)*W_ + w];
            tile[row*65 + col] = f2bf(val);
        }
        __syncthreads();
        int pixel = t >> 2;
        int csub  = (t & 3) * 16;
        int w = w0 + pixel;
        if (w < W_) {
            union { ushortT u[16]; uint4 q[2]; } vals;
            #pragma unroll
            for (int j = 0; j < 16; ++j)
                vals.u[j] = tile[(csub + j)*65 + pixel];
            size_t dst = (((size_t)b*HP_ + (h+1))*WP_ + (w+1))*C_ + c0 + csub;
            *(uint4*)(Xp + dst)     = vals.q[0];
            *(uint4*)(Xp + dst + 8) = vals.q[1];
        }
    }
}

// Pre-pass 2: W1 [oc][c][3][3] fp32 -> W1t [rs][oc][c] bf16
__global__ __launch_bounds__(256) void prep_w1(const float* __restrict__ W1,
                                               ushortT* __restrict__ W1t) {
    int t = blockIdx.x * 256 + threadIdx.x;
    if (t >= OC_*C_) return;
    const float* src = W1 + (size_t)t * 9;
    #pragma unroll
    for (int rs = 0; rs < 9; ++rs)
        W1t[(size_t)rs*OC_*C_ + t] = f2bf(src[rs]);
}

// Pre-pass 3: Wc[18][512], Wb[36][512] -> Whb[64][512] bf16 (rows 54..63 zero)
__global__ __launch_bounds__(256) void prep_whb(const float* __restrict__ Wc,
                                                const float* __restrict__ Wb,
                                                ushortT* __restrict__ Whb) {
    int t = blockIdx.x * 256 + threadIdx.x;
    if (t >= 64*512) return;
    int o = t >> 9, oc = t & 511;
    float v = 0.f;
    if (o < 18) v = Wc[o*512 + oc];
    else if (o < 54) v = Wb[(o-18)*512 + oc];
    Whb[t] = f2bf(v);
}

// Pre-pass 4: init output with head biases, float4 stores.
__global__ __launch_bounds__(256) void init_out(const float* __restrict__ bc,
                                                const float* __restrict__ bb,
                                                float* __restrict__ out) {
    int i = blockIdx.x * 256 + threadIdx.x;   // float4 index
    if (i >= OUT_TOTAL_/4) return;
    int base = i * 4;
    float4 v;
    #pragma unroll
    for (int j = 0; j < 4; ++j) {
        int idx = base + j;
        float val = (idx < OUT0_) ? bc[idx % 18] : bb[(idx - OUT0_) % 36];
        (&v.x)[j] = val;
    }
    ((float4*)out)[i] = v;
}

// ---------------------------------------------------------------------------
// Main fused kernel: implicit-GEMM conv3x3 (M=268800, N=512 in 4 blocks of
// 128, K=2304, BK=64) + bias + ReLU + 1x1 head GEMM, atomic partials.
//
// BK=64: Asm/Bsm 32KB still fits under the 34.8KB Fsm union -> occupancy
// unchanged, barrier-pairs halved (36 vs 72), 32 MFMA per pair.
// XOR swizzle (chunk ^= row&7) keeps the stride-128B fragment reads 2-way.
#define FP_ 136   // Fsm row stride (elements); 272B rows, 16B-aligned

#define GRID_GROUPS ((MTILES + 7) / 8)            // 263
#define CONV_GRID   (GRID_GROUPS * 32)            // 8416 (16 idle blocks)

__global__ __launch_bounds__(256, 4) void conv_rpn(
    const ushortT* __restrict__ Xp, const ushortT* __restrict__ W1t,
    const float* __restrict__ b1,  const ushortT* __restrict__ Whb,
    float* __restrict__ out)
{
    extern __shared__ ushortT smem[];
    ushortT* Asm = smem;              // [128][64] 16KB (K-loop)
    ushortT* Bsm = smem + 128*64;     // [128][64] 16KB (K-loop)
    ushortT* Fsm = smem;              // [128][FP_] 34KB (epilogue, overlaps)

    const int tid  = threadIdx.x;
    const int wave = tid >> 6;
    const int lane = tid & 63;
    const int col  = lane & 15;
    const int quad = lane >> 4;

    // XCD-aware decode (same-XCD grouping of the 4 nblks of one mtile).
    const int bidx   = blockIdx.x;
    const int grp    = bidx >> 5;
    const int within = bidx & 31;
    const int mtile  = grp * 8 + (within & 7);
    const int nblk   = within >> 3;
    if (mtile >= MTILES) return;
    const int oc0 = nblk << 7;

    // Staging: 4 issues/wave, each covers 8 rows x 64k (8 chunks of 8 elems).
    // Lane (r8=lane>>3, c=lane&7) fetches logical chunk c^r8 of row r8.
    const int r8     = lane >> 3;
    const int lchunk = ((lane & 7) ^ r8) * 8;

    size_t pixbase[4];
    #pragma unroll
    for (int i = 0; i < 4; ++i) {
        int m = mtile*128 + wave*32 + i*8 + r8;
        int b = m / (H_*W_);
        int rem = m % (H_*W_);
        int h = rem / W_;
        int w = rem % W_;
        pixbase[i] = (((size_t)b*HP_ + h)*WP_ + w)*C_ + lchunk;
    }
    const size_t bbase = ((size_t)(oc0 + wave*32 + r8))*C_ + lchunk;

    f32x4 acc[4][4] = {};
    const int wm = (wave & 1) * 64;
    const int wn = (wave >> 1) * 64;
    const int c7 = col & 7;   // read de-swizzle key (row&7 == col&7)

    for (int rs = 0; rs < 9; ++rs) {
        const int roff = ((rs/3)*WP_ + (rs%3)) * C_;
        const size_t wsrc = (size_t)rs*OC_*C_;
        for (int cs = 0; cs < C_; cs += 64) {
            __syncthreads();
            #pragma unroll
            for (int i = 0; i < 4; ++i) {
                const ushortT* g = Xp + pixbase[i] + roff + cs;
                ushortT* l = Asm + (wave*32 + i*8)*64;
                __builtin_amdgcn_global_load_lds(
                    (const __attribute__((address_space(1))) uint32_t*)g,
                    (__attribute__((address_space(3))) uint32_t*)l, 16, 0, 0);
            }
            #pragma unroll
            for (int i = 0; i < 4; ++i) {
                const ushortT* g = W1t + wsrc + bbase + (size_t)i*8*C_ + cs;
                ushortT* l = Bsm + (wave*32 + i*8)*64;
                __builtin_amdgcn_global_load_lds(
                    (const __attribute__((address_space(1))) uint32_t*)g,
                    (__attribute__((address_space(3))) uint32_t*)l, 16, 0, 0);
            }
            __syncthreads();

            #pragma unroll
            for (int kk = 0; kk < 2; ++kk) {
                const int pcA = ((kk*4 + quad) ^ c7) * 8;
                bf16x8 af[4], bfr[4];
                #pragma unroll
                for (int mt = 0; mt < 4; ++mt)
                    af[mt] = *(const bf16x8*)&Asm[(wm + mt*16 + col)*64 + pcA];
                #pragma unroll
                for (int nt = 0; nt < 4; ++nt)
                    bfr[nt] = *(const bf16x8*)&Bsm[(wn + nt*16 + col)*64 + pcA];
                #pragma unroll
                for (int mt = 0; mt < 4; ++mt)
                    #pragma unroll
                    for (int nt = 0; nt < 4; ++nt)
                        acc[mt][nt] = __builtin_amdgcn_mfma_f32_16x16x32_bf16(
                            af[mt], bfr[nt], acc[mt][nt], 0, 0, 0);
            }
        }
    }

    // Epilogue: +b1, ReLU, feat tile -> LDS (bf16). Fsm overlaps Asm/Bsm.
    __syncthreads();
    float b1v[4];
    #pragma unroll
    for (int nt = 0; nt < 4; ++nt) b1v[nt] = b1[oc0 + wn + nt*16 + col];
    #pragma unroll
    for (int mt = 0; mt < 4; ++mt)
        #pragma unroll
        for (int nt = 0; nt < 4; ++nt)
            #pragma unroll
            for (int rg = 0; rg < 4; ++rg) {
                float v = acc[mt][nt][rg] + b1v[nt];
                v = fmaxf(v, 0.f);
                Fsm[(wm + mt*16 + quad*4 + rg)*FP_ + wn + nt*16 + col] = f2bf(v);
            }
    __syncthreads();

    // Head GEMM: M=128 pixels, N=64 (54 used), K=128 (this block's oc slice)
    f32x4 hacc[2][4] = {};
    #pragma unroll
    for (int ks = 0; ks < 4; ++ks) {
        bf16x8 ah[2];
        #pragma unroll
        for (int mt = 0; mt < 2; ++mt)
            ah[mt] = *(const bf16x8*)&Fsm[(wave*32 + mt*16 + col)*FP_ + ks*32 + quad*8];
        #pragma unroll
        for (int nt = 0; nt < 4; ++nt) {
            bf16x8 bh = *(const bf16x8*)&Whb[(nt*16 + col)*512 + oc0 + ks*32 + quad*8];
            #pragma unroll
            for (int mt = 0; mt < 2; ++mt)
                hacc[mt][nt] = __builtin_amdgcn_mfma_f32_16x16x32_bf16(
                    ah[mt], bh, hacc[mt][nt], 0, 0, 0);
        }
    }

    // Atomic partial accumulation into interleaved outputs.
    #pragma unroll
    for (int mt = 0; mt < 2; ++mt) {
        int mbase = mtile*128 + wave*32 + mt*16 + quad*4;
        #pragma unroll
        for (int nt = 0; nt < 4; ++nt) {
            int o = nt*16 + col;
            #pragma unroll
            for (int rg = 0; rg < 4; ++rg) {
                float v = hacc[mt][nt][rg];
                size_t p = (size_t)(mbase + rg);
                if (o < 18)      atomicAdd(out + p*18 + o, v);
                else if (o < 54) atomicAdd(out + OUT0_ + p*36 + (o - 18), v);
            }
        }
    }
}

// ---------------------------------------------------------------------------
extern "C" void kernel_launch(void* const* d_in, const int* in_sizes, int n_in,
                              void* d_out, int out_size, void* d_ws, size_t ws_size,
                              hipStream_t stream) {
    const float* X  = (const float*)d_in[0];
    const float* W1 = (const float*)d_in[1];
    const float* b1 = (const float*)d_in[2];
    const float* Wc = (const float*)d_in[3];
    const float* bc = (const float*)d_in[4];
    const float* Wb = (const float*)d_in[5];
    const float* bb = (const float*)d_in[6];
    float* out = (float*)d_out;

    ushortT* Xp  = (ushortT*)d_ws;
    ushortT* W1t = (ushortT*)((char*)d_ws + W1T_OFF);
    ushortT* Whb = (ushortT*)((char*)d_ws + WHB_OFF);

    zero_halo<<<(4*1076*32 + 255)/256, 256, 0, stream>>>(Xp);
    pad_transpose<<<B_*H_*6, 256, 0, stream>>>(X, Xp);
    prep_w1<<<(OC_*C_ + 255)/256, 256, 0, stream>>>(W1, W1t);
    prep_whb<<<(64*512 + 255)/256, 256, 0, stream>>>(Wc, Wb, Whb);
    init_out<<<(OUT_TOTAL_/4 + 255)/256, 256, 0, stream>>>(bc, bb, out);
    conv_rpn<<<CONV_GRID, 256, 128*FP_*sizeof(ushortT), stream>>>(
        Xp, W1t, b1, Whb, out);
}